// Round 1
// baseline (514.848 us; speedup 1.0000x reference)
//
#include <hip/hip_runtime.h>
#include <hip/hip_bf16.h>
#include <cstddef>

namespace {

constexpr int kB = 8, kV = 4096, kP = 32, kCin = 64, kN = 16;
constexpr int kCout = 128, kJ = 512;      // Cin * R * (L_MAX+1) = 64*2*4
constexpr int kG = 16;                    // v's per block
constexpr int kJC = 32;                   // W j-chunk staged in LDS
constexpr int kBlocks = kB * kV / kG;     // 2048

struct __align__(16) SM {
    float zT[kJ][kG];                     // 32 KB, [j][g], j = c*8 + r*4 + l
    union {
        struct {
            float patch[2][kP][kCin];     // 16 KB
            float ck[2][kP][2 * kN];      // 8 KB, [hv][p][rn], rn = r*16+n
            int pidx[2][kP];
        } s1;
        float Wt[kCout][kJC + 1];         // 16.5 KB (+1 pad: 2-way = free)
    } u;
};

__global__ __launch_bounds__(256, 2)
void fused(const float* __restrict__ signal,
           const int* __restrict__ pidx_g,
           const float* __restrict__ ck_g,
           const float* __restrict__ W,
           const float* __restrict__ bias,
           float* __restrict__ out)
{
    __shared__ SM sm;
    const int t = threadIdx.x;
    const int b = blockIdx.x >> 8;              // 256 blocks per batch
    const int v_base = (blockIdx.x & 255) * kG;

    const int hv = t >> 7;                      // which of 2 v's this step
    const int c  = t & 63;
    const int r  = (t >> 6) & 1;

    // ---------------- Phase 1: per-point SH conv -> z in LDS ----------------
    for (int gg = 0; gg < kG / 2; ++gg) {
        const int v0 = v_base + gg * 2;

        if (t < 64) {                           // stage neighbor indices
            const int lp = t & 31, lhv = t >> 5;
            sm.u.s1.pidx[lhv][lp] =
                pidx_g[((((size_t)b * kV + v0 + lhv) * kP + lp) << 1) + 1];
        }
        {                                       // stage conv_kernel tile (2x1024 f32)
            const int lhv = t >> 7;
            const int ql = (t & 127) * 2;
            const float4* src =
                (const float4*)(ck_g + ((size_t)b * kV + v0 + lhv) * (kP * 2 * kN));
            float4* dst = (float4*)&sm.u.s1.ck[lhv][0][0];
            dst[ql]     = src[ql];
            dst[ql + 1] = src[ql + 1];
        }
        __syncthreads();
        #pragma unroll
        for (int k = 0; k < 16; ++k) {          // stage gathered patches (2x32x64)
            const int flat = k * 256 + t;
            const int cc = flat & 63;
            const int pp = (flat >> 6) & 31;
            const int hh = flat >> 11;
            const int vs = sm.u.s1.pidx[hh][pp];
            sm.u.s1.patch[hh][pp][cc] = signal[((size_t)b * kV + vs) * kCin + cc];
        }
        __syncthreads();

        // y[n] = sum_p ck[p][r*16+n] * patch[p][c]   (16 n per thread)
        float y[16];
        #pragma unroll
        for (int n = 0; n < 16; ++n) y[n] = 0.f;
        const float4* ckrow = (const float4*)&sm.u.s1.ck[hv][0][0]; // 8 f4 per p
        const float*  prow  = &sm.u.s1.patch[hv][0][0];
        #pragma unroll 4
        for (int p = 0; p < kP; ++p) {
            const float a = prow[p * kCin + c];
            const float4 k0 = ckrow[p * 8 + r * 4 + 0];
            const float4 k1 = ckrow[p * 8 + r * 4 + 1];
            const float4 k2 = ckrow[p * 8 + r * 4 + 2];
            const float4 k3 = ckrow[p * 8 + r * 4 + 3];
            y[0]  = fmaf(a, k0.x, y[0]);  y[1]  = fmaf(a, k0.y, y[1]);
            y[2]  = fmaf(a, k0.z, y[2]);  y[3]  = fmaf(a, k0.w, y[3]);
            y[4]  = fmaf(a, k1.x, y[4]);  y[5]  = fmaf(a, k1.y, y[5]);
            y[6]  = fmaf(a, k1.z, y[6]);  y[7]  = fmaf(a, k1.w, y[7]);
            y[8]  = fmaf(a, k2.x, y[8]);  y[9]  = fmaf(a, k2.y, y[9]);
            y[10] = fmaf(a, k2.z, y[10]); y[11] = fmaf(a, k2.w, y[11]);
            y[12] = fmaf(a, k3.x, y[12]); y[13] = fmaf(a, k3.y, y[13]);
            y[14] = fmaf(a, k3.z, y[14]); y[15] = fmaf(a, k3.w, y[15]);
        }
        // square -> SH power per degree l -> sqrt
        float z0 = y[0] * y[0];
        float z1 = y[1]*y[1] + y[2]*y[2] + y[3]*y[3];
        float z2 = y[4]*y[4] + y[5]*y[5] + y[6]*y[6] + y[7]*y[7] + y[8]*y[8];
        float z3 = 0.f;
        #pragma unroll
        for (int n = 9; n < 16; ++n) z3 += y[n] * y[n];
        z0 = sqrtf(fmaxf(z0, 1e-4f));
        z1 = sqrtf(fmaxf(z1, 1e-4f));
        z2 = sqrtf(fmaxf(z2, 1e-4f));
        z3 = sqrtf(fmaxf(z3, 1e-4f));
        const int g  = gg * 2 + hv;
        const int jb = c * 8 + r * 4;
        sm.zT[jb + 0][g] = z0;   // known 64-way conflict on these 4 stores;
        sm.zT[jb + 1][g] = z1;   // ~9% est. cost, revisit with SQ_LDS_BANK_CONFLICT
        sm.zT[jb + 2][g] = z2;
        sm.zT[jb + 3][g] = z3;
        __syncthreads();
    }

    // ---------------- Phase 2: out[g][i] = relu(W @ z + bias) ----------------
    const int i  = t & 127;
    const int gq = t >> 7;      // 8-g register tile
    float acc[8];
    #pragma unroll
    for (int e = 0; e < 8; ++e) acc[e] = 0.f;

    for (int jc = 0; jc < kJ / kJC; ++jc) {
        const int j0 = jc * kJC;
        {   // stage W[i][j0..j0+31] -> Wt (coalesced 128B per row-pair)
            const int row  = t >> 1;
            const int col0 = (t & 1) * 16;
            const float4* W4 = (const float4*)(W + (size_t)row * kJ + j0 + col0);
            const float4 w0 = W4[0], w1 = W4[1], w2 = W4[2], w3 = W4[3];
            float* dst = &sm.u.Wt[row][col0];
            dst[0]=w0.x;  dst[1]=w0.y;  dst[2]=w0.z;  dst[3]=w0.w;
            dst[4]=w1.x;  dst[5]=w1.y;  dst[6]=w1.z;  dst[7]=w1.w;
            dst[8]=w2.x;  dst[9]=w2.y;  dst[10]=w2.z; dst[11]=w2.w;
            dst[12]=w3.x; dst[13]=w3.y; dst[14]=w3.z; dst[15]=w3.w;
        }
        __syncthreads();
        #pragma unroll 8
        for (int jj = 0; jj < kJC; ++jj) {
            const float w = sm.u.Wt[i][jj];                  // 2-way, free
            const float4* zr = (const float4*)&sm.zT[j0 + jj][0];
            const float4 za = zr[gq * 2];                    // lane-uniform b128
            const float4 zb = zr[gq * 2 + 1];                // broadcast, free
            acc[0] = fmaf(w, za.x, acc[0]);
            acc[1] = fmaf(w, za.y, acc[1]);
            acc[2] = fmaf(w, za.z, acc[2]);
            acc[3] = fmaf(w, za.w, acc[3]);
            acc[4] = fmaf(w, zb.x, acc[4]);
            acc[5] = fmaf(w, zb.y, acc[5]);
            acc[6] = fmaf(w, zb.z, acc[6]);
            acc[7] = fmaf(w, zb.w, acc[7]);
        }
        __syncthreads();
    }
    const float bi = bias[i];
    #pragma unroll
    for (int e = 0; e < 8; ++e) {
        const int g = gq * 8 + e;
        out[((size_t)b * kV + v_base + g) * kCout + i] = fmaxf(acc[e] + bi, 0.f);
    }
}

} // namespace

extern "C" void kernel_launch(void* const* d_in, const int* in_sizes, int n_in,
                              void* d_out, int out_size, void* d_ws, size_t ws_size,
                              hipStream_t stream) {
    const float* signal = (const float*)d_in[0];
    const int*   pidx   = (const int*)d_in[1];
    const float* ck     = (const float*)d_in[2];
    const float* W      = (const float*)d_in[3];
    const float* bias   = (const float*)d_in[4];
    float* out = (float*)d_out;
    fused<<<dim3(kBlocks), dim3(256), 0, stream>>>(signal, pidx, ck, W, bias, out);
}

// Round 3
// 240.791 us; speedup vs baseline: 2.1381x; 2.1381x over previous
//
#include <hip/hip_runtime.h>
#include <cstddef>

namespace {

constexpr int kV = 4096;
constexpr int kBlocks = 8 * kV / 16;  // 2048 blocks, 16 v each

typedef float f32x16 __attribute__((ext_vector_type(16)));
typedef float f32x4  __attribute__((ext_vector_type(4)));
typedef short bf16x8 __attribute__((ext_vector_type(8)));

union U8 { unsigned u[4]; uint4 q; bf16x8 v; };

// round-to-nearest-even fp32->bf16, packed pair (a -> lo16, b -> hi16)
__device__ inline unsigned pk_bf16(float a, float b) {
    unsigned ua = __float_as_uint(a);
    unsigned ub = __float_as_uint(b);
    ua = (ua + 0x7FFFu + ((ua >> 16) & 1u)) >> 16;
    ub = (ub + 0x7FFFu + ((ub >> 16) & 1u)) & 0xFFFF0000u;
    return ua | ub;
}

// One-shot fp32 -> bf16 conversion of kernel_weights into d_ws (re-done every
// launch: d_ws is re-poisoned before each timed replay).
__global__ void convW(const float* __restrict__ W, unsigned* __restrict__ Wb) {
    const int i = blockIdx.x * 256 + threadIdx.x;   // 32768 = 65536/2
    const float2 w2 = ((const float2*)W)[i];
    Wb[i] = pk_bf16(w2.x, w2.y);
}

__global__ __launch_bounds__(256, 4)
void fused(const float* __restrict__ signal,
           const int* __restrict__ pidx_g,
           const float* __restrict__ ck_g,
           const unsigned short* __restrict__ Wb,   // bf16 weights from convW
           const float* __restrict__ bias,
           float* __restrict__ out)
{
    // zbf: phase-2 A operand, [g][j], j = c*8 + r*4 + l (pad 512->520 keeps
    // rows 16B-aligned). patchI: per-WAVE p-pair-interleaved signal tile,
    // dword = {p even lo16, p odd hi16}; row pp holds k-pair (2pp,2pp+1),
    // col = channel c. All cross-lane LDS ordering via __syncthreads only.
    __shared__ __align__(16) unsigned short zbf[16][520];   // 16.25 KB
    __shared__ unsigned patchI[4][16][64];                  // 16 KB

    const int t = threadIdx.x;
    const int b = blockIdx.x >> 8;
    const int v_base = (blockIdx.x & 255) * 16;
    const int w    = t >> 6;
    const int lane = t & 63;
    const int n31  = lane & 31;
    const int h    = lane >> 5;

    unsigned (*pI)[64] = patchI[w];
    const float* sgb = signal + (size_t)b * kV * 64;

    // ---------------- Phase 1: MFMA 32x32x16, D[m=rn][n=c] ----------------
    for (int vg = 0; vg < 4; ++vg) {
        const int g = vg * 4 + w;                 // wave-private v
        const size_t bv = (size_t)b * kV + (v_base + g);
        const int vsv = pidx_g[(bv * 32 + n31) * 2 + 1];   // lane p holds vs_p
        const float* ckv = ck_g + bv * 1024;               // [32 p][32 rn]

        __syncthreads();   // WAR: previous vg's frag reads drained (all waves)

        // stage gathered signal, register-transposed to bf16 pairs
        #pragma unroll
        for (int pp = 0; pp < 16; ++pp) {
            const int vs0 = __builtin_amdgcn_readlane(vsv, 2 * pp);
            const int vs1 = __builtin_amdgcn_readlane(vsv, 2 * pp + 1);
            const float s0 = sgb[(size_t)vs0 * 64 + lane];
            const float s1 = sgb[(size_t)vs1 * 64 + lane];
            pI[pp][lane] = pk_bf16(s0, s1);
        }

        // A-fragments straight from global (same-lane data, no LDS round-trip)
        // A[m=rn=n31][k], k = ks*16 + 8h + 2*j2 + {0,1}
        U8 A0, A1;
        #pragma unroll
        for (int j2 = 0; j2 < 4; ++j2) {
            const int p0 = 8 * h + 2 * j2;
            A0.u[j2] = pk_bf16(ckv[(p0     ) * 32 + n31], ckv[(p0 +  1) * 32 + n31]);
            A1.u[j2] = pk_bf16(ckv[(p0 + 16) * 32 + n31], ckv[(p0 + 17) * 32 + n31]);
        }

        __syncthreads();   // RAW: staging visible to all lanes

        U8 B00, B01, B10, B11;   // B[k][n=c], c-tiles 0..31 / 32..63
        #pragma unroll
        for (int j2 = 0; j2 < 4; ++j2) {
            B00.u[j2] = pI[    4 * h + j2][n31];
            B01.u[j2] = pI[    4 * h + j2][n31 + 32];
            B10.u[j2] = pI[8 + 4 * h + j2][n31];
            B11.u[j2] = pI[8 + 4 * h + j2][n31 + 32];
        }

        f32x16 acc0, acc1;
        #pragma unroll
        for (int j = 0; j < 16; ++j) { acc0[j] = 0.f; acc1[j] = 0.f; }
        acc0 = __builtin_amdgcn_mfma_f32_32x32x16_bf16(A0.v, B00.v, acc0, 0, 0, 0);
        acc1 = __builtin_amdgcn_mfma_f32_32x32x16_bf16(A0.v, B01.v, acc1, 0, 0, 0);
        acc0 = __builtin_amdgcn_mfma_f32_32x32x16_bf16(A1.v, B10.v, acc0, 0, 0, 0);
        acc1 = __builtin_amdgcn_mfma_f32_32x32x16_bf16(A1.v, B11.v, acc1, 0, 0, 0);

        // C-layout: col=lane&31 (=c), row=(reg&3)+8*(reg>>2)+4*h (=rn=r*16+n).
        #pragma unroll
        for (int ct = 0; ct < 2; ++ct) {
            const f32x16 a = ct ? acc1 : acc0;
            float s[16];
            #pragma unroll
            for (int j = 0; j < 16; ++j) s[j] = a[j] * a[j];
            // h=0 rows {0-3,8-11,16-19,24-27}; h=1 rows {4-7,12-15,20-23,28-31}
            const float o00 = s[0], o10 = s[1] + s[2] + s[3];
            const float o20 = s[4], o30 = s[5] + s[6] + s[7];
            const float o01 = s[8], o11 = s[9] + s[10] + s[11];
            const float o21 = s[12], o31 = s[13] + s[14] + s[15];
            const float x0 = s[0] + s[1] + s[2] + s[3];
            const float x1 = s[4] + s[5] + s[6] + s[7];
            const float x2 = s[8] + s[9] + s[10] + s[11];
            const float x3 = s[12] + s[13] + s[14] + s[15];
            const float e0 = __shfl_xor(h ? x0 : o20, 32);
            const float e1 = __shfl_xor(h ? x1 : o30, 32);
            const float e2 = __shfl_xor(h ? x2 : o21, 32);
            const float e3 = __shfl_xor(h ? x3 : o31, 32);
            if (h == 0) {
                const float z00 = sqrtf(fmaxf(o00,      1e-4f));
                const float z10 = sqrtf(fmaxf(o10,      1e-4f));
                const float z20 = sqrtf(fmaxf(o20 + e0, 1e-4f));
                const float z30 = sqrtf(fmaxf(o30 + e1, 1e-4f));
                const float z01 = sqrtf(fmaxf(o01,      1e-4f));
                const float z11 = sqrtf(fmaxf(o11,      1e-4f));
                const float z21 = sqrtf(fmaxf(o21 + e2, 1e-4f));
                const float z31 = sqrtf(fmaxf(o31 + e3, 1e-4f));
                uint4 d;
                d.x = pk_bf16(z00, z10);
                d.y = pk_bf16(z20, z30);
                d.z = pk_bf16(z01, z11);
                d.w = pk_bf16(z21, z31);
                *(uint4*)&zbf[g][(n31 + 32 * ct) * 8] = d;   // j = c*8+r*4+l
            }
        }
    }
    __syncthreads();   // zbf complete, visible to all waves

    // ------- Phase 2: MFMA 16x16x32, D[m=g][n=i], K=512, B = bf16 global ---
    const int m15 = lane & 15;          // A row g AND D col i
    const int q   = lane >> 4;          // k-quad
    f32x4 pa0, pa1;
    #pragma unroll
    for (int j = 0; j < 4; ++j) { pa0[j] = 0.f; pa1[j] = 0.f; }
    const int i0 = w * 32 + m15;
    const int i1 = w * 32 + 16 + m15;
    #pragma unroll 4
    for (int ks = 0; ks < 16; ++ks) {
        U8 Az, Bw0, Bw1;
        Az.q  = *(const uint4*)&zbf[m15][ks * 32 + q * 8];
        Bw0.q = *(const uint4*)&Wb[(size_t)i0 * 512 + ks * 32 + q * 8];
        Bw1.q = *(const uint4*)&Wb[(size_t)i1 * 512 + ks * 32 + q * 8];
        pa0 = __builtin_amdgcn_mfma_f32_16x16x32_bf16(Az.v, Bw0.v, pa0, 0, 0, 0);
        pa1 = __builtin_amdgcn_mfma_f32_16x16x32_bf16(Az.v, Bw1.v, pa1, 0, 0, 0);
    }
    const float bi0 = bias[i0], bi1 = bias[i1];
    #pragma unroll
    for (int reg = 0; reg < 4; ++reg) {
        const int g = q * 4 + reg;                       // D row = g
        const size_t row = ((size_t)b * kV + v_base + g) * 128;
        out[row + i0] = fmaxf(pa0[reg] + bi0, 0.f);
        out[row + i1] = fmaxf(pa1[reg] + bi1, 0.f);
    }
}

} // namespace

extern "C" void kernel_launch(void* const* d_in, const int* in_sizes, int n_in,
                              void* d_out, int out_size, void* d_ws, size_t ws_size,
                              hipStream_t stream) {
    const float* signal = (const float*)d_in[0];
    const int*   pidx   = (const int*)d_in[1];
    const float* ck     = (const float*)d_in[2];
    const float* W      = (const float*)d_in[3];
    const float* bias   = (const float*)d_in[4];
    float* out = (float*)d_out;
    unsigned* Wb = (unsigned*)d_ws;     // 128 KB bf16 weights

    convW<<<dim3(128), dim3(256), 0, stream>>>(W, Wb);
    fused<<<dim3(kBlocks), dim3(256), 0, stream>>>(
        signal, pidx, ck, (const unsigned short*)Wb, bias, out);
}

// Round 4
// 238.694 us; speedup vs baseline: 2.1569x; 1.0088x over previous
//
#include <hip/hip_runtime.h>
#include <cstddef>

namespace {

constexpr int kV = 4096;
constexpr int kBlocks = 8 * kV / 16;  // 2048 blocks, 16 v each

typedef float f32x16 __attribute__((ext_vector_type(16)));
typedef float f32x4  __attribute__((ext_vector_type(4)));
typedef short bf16x8 __attribute__((ext_vector_type(8)));

union U8 { unsigned u[4]; uint4 q; bf16x8 v; };

// round-to-nearest-even fp32->bf16, packed pair (a -> lo16, b -> hi16)
__device__ inline unsigned pk_bf16(float a, float b) {
    unsigned ua = __float_as_uint(a);
    unsigned ub = __float_as_uint(b);
    ua = (ua + 0x7FFFu + ((ua >> 16) & 1u)) >> 16;
    ub = (ub + 0x7FFFu + ((ub >> 16) & 1u)) & 0xFFFF0000u;
    return ua | ub;
}

// fp32 -> bf16 conversion of kernel_weights into d_ws (re-done every launch:
// d_ws is re-poisoned before each timed replay).
__global__ void convW(const float* __restrict__ W, unsigned* __restrict__ Wb) {
    const int i = blockIdx.x * 256 + threadIdx.x;   // 32768 = 65536/2
    const float2 w2 = ((const float2*)W)[i];
    Wb[i] = pk_bf16(w2.x, w2.y);
}

__global__ __launch_bounds__(256, 4)
void fused(const float* __restrict__ signal,
           const int* __restrict__ pidx_g,
           const float* __restrict__ ck_g,
           const unsigned short* __restrict__ Wb,   // bf16 weights from convW
           const float* __restrict__ bias,
           float* __restrict__ out)
{
    // zbf: phase-2 A operand, [g][j], j = c*8 + r*4 + l (pad 512->520 keeps
    // rows 16B-aligned). patchI: per-WAVE p-pair-interleaved signal tile,
    // dword = {p even lo16, p odd hi16}; row pp holds k-pair (2pp,2pp+1),
    // col = channel c. Cross-lane LDS ordering via __syncthreads only.
    __shared__ __align__(16) unsigned short zbf[16][520];   // 16.25 KB
    __shared__ unsigned patchI[4][16][64];                  // 16 KB

    const int t = threadIdx.x;
    const int b = blockIdx.x >> 8;
    const int v_base = (blockIdx.x & 255) * 16;
    const int w    = t >> 6;
    const int lane = t & 63;
    const int n31  = lane & 31;
    const int h    = lane >> 5;

    unsigned (*pI)[64] = patchI[w];
    const float* sgb = signal + (size_t)b * kV * 64;

    // Hoisted neighbor indices for all 4 wave-private v's (lane p holds vs_p).
    int vsl[4];
    #pragma unroll
    for (int vg = 0; vg < 4; ++vg)
        vsl[vg] = pidx_g[((((size_t)b * kV + v_base + vg * 4 + w) * 32) + n31) * 2 + 1];

    // Prefetch registers for the NEXT vg (issued ~a full MFMA stage early so
    // global-load latency hides behind sync + frag reads + MFMA + epilogue).
    float sP[32];   // gathered signal rows, (p, c=lane)
    float cP[16];   // ck column n31, p in A-frag order

    auto prefetch = [&](int vg) {
        const size_t bv = (size_t)b * kV + (v_base + vg * 4 + w);
        const float* ckv = ck_g + bv * 1024;               // [32 p][32 rn]
        #pragma unroll
        for (int pp = 0; pp < 16; ++pp) {
            const int vs0 = __builtin_amdgcn_readlane(vsl[vg], 2 * pp);
            const int vs1 = __builtin_amdgcn_readlane(vsl[vg], 2 * pp + 1);
            sP[2 * pp    ] = sgb[(size_t)vs0 * 64 + lane];
            sP[2 * pp + 1] = sgb[(size_t)vs1 * 64 + lane];
        }
        #pragma unroll
        for (int j2 = 0; j2 < 4; ++j2) {
            const int p0 = 8 * h + 2 * j2;
            cP[4 * j2 + 0] = ckv[(p0     ) * 32 + n31];
            cP[4 * j2 + 1] = ckv[(p0 +  1) * 32 + n31];
            cP[4 * j2 + 2] = ckv[(p0 + 16) * 32 + n31];
            cP[4 * j2 + 3] = ckv[(p0 + 17) * 32 + n31];
        }
    };

    prefetch(0);

    // ---------------- Phase 1: MFMA 32x32x16, D[m=rn][n=c] ----------------
    #pragma unroll
    for (int vg = 0; vg < 4; ++vg) {
        const int g = vg * 4 + w;                 // wave-private v

        __syncthreads();   // WAR: previous vg's frag reads drained

        // consume prefetch: stage signal (bf16 p-pairs) + build A-frags
        #pragma unroll
        for (int pp = 0; pp < 16; ++pp)
            pI[pp][lane] = pk_bf16(sP[2 * pp], sP[2 * pp + 1]);

        // A[m=rn=n31][k], k = ks*16 + 8h + 2*j2 + {0,1} (same-lane data)
        U8 A0, A1;
        #pragma unroll
        for (int j2 = 0; j2 < 4; ++j2) {
            A0.u[j2] = pk_bf16(cP[4 * j2 + 0], cP[4 * j2 + 1]);
            A1.u[j2] = pk_bf16(cP[4 * j2 + 2], cP[4 * j2 + 3]);
        }

        if (vg < 3) prefetch(vg + 1);   // issue next loads into freed regs

        __syncthreads();   // RAW: staging visible to all lanes

        U8 B00, B01, B10, B11;   // B[k][n=c], c-tiles 0..31 / 32..63
        #pragma unroll
        for (int j2 = 0; j2 < 4; ++j2) {
            B00.u[j2] = pI[    4 * h + j2][n31];
            B01.u[j2] = pI[    4 * h + j2][n31 + 32];
            B10.u[j2] = pI[8 + 4 * h + j2][n31];
            B11.u[j2] = pI[8 + 4 * h + j2][n31 + 32];
        }

        f32x16 acc0, acc1;
        #pragma unroll
        for (int j = 0; j < 16; ++j) { acc0[j] = 0.f; acc1[j] = 0.f; }
        acc0 = __builtin_amdgcn_mfma_f32_32x32x16_bf16(A0.v, B00.v, acc0, 0, 0, 0);
        acc1 = __builtin_amdgcn_mfma_f32_32x32x16_bf16(A0.v, B01.v, acc1, 0, 0, 0);
        acc0 = __builtin_amdgcn_mfma_f32_32x32x16_bf16(A1.v, B10.v, acc0, 0, 0, 0);
        acc1 = __builtin_amdgcn_mfma_f32_32x32x16_bf16(A1.v, B11.v, acc1, 0, 0, 0);

        // C-layout: col=lane&31 (=c), row=(reg&3)+8*(reg>>2)+4*h (=rn=r*16+n).
        #pragma unroll
        for (int ct = 0; ct < 2; ++ct) {
            const f32x16 a = ct ? acc1 : acc0;
            float s[16];
            #pragma unroll
            for (int j = 0; j < 16; ++j) s[j] = a[j] * a[j];
            // h=0 rows {0-3,8-11,16-19,24-27}; h=1 rows {4-7,12-15,20-23,28-31}
            const float o00 = s[0], o10 = s[1] + s[2] + s[3];
            const float o20 = s[4], o30 = s[5] + s[6] + s[7];
            const float o01 = s[8], o11 = s[9] + s[10] + s[11];
            const float o21 = s[12], o31 = s[13] + s[14] + s[15];
            const float x0 = s[0] + s[1] + s[2] + s[3];
            const float x1 = s[4] + s[5] + s[6] + s[7];
            const float x2 = s[8] + s[9] + s[10] + s[11];
            const float x3 = s[12] + s[13] + s[14] + s[15];
            const float e0 = __shfl_xor(h ? x0 : o20, 32);
            const float e1 = __shfl_xor(h ? x1 : o30, 32);
            const float e2 = __shfl_xor(h ? x2 : o21, 32);
            const float e3 = __shfl_xor(h ? x3 : o31, 32);
            if (h == 0) {
                const float z00 = sqrtf(fmaxf(o00,      1e-4f));
                const float z10 = sqrtf(fmaxf(o10,      1e-4f));
                const float z20 = sqrtf(fmaxf(o20 + e0, 1e-4f));
                const float z30 = sqrtf(fmaxf(o30 + e1, 1e-4f));
                const float z01 = sqrtf(fmaxf(o01,      1e-4f));
                const float z11 = sqrtf(fmaxf(o11,      1e-4f));
                const float z21 = sqrtf(fmaxf(o21 + e2, 1e-4f));
                const float z31 = sqrtf(fmaxf(o31 + e3, 1e-4f));
                uint4 d;
                d.x = pk_bf16(z00, z10);
                d.y = pk_bf16(z20, z30);
                d.z = pk_bf16(z01, z11);
                d.w = pk_bf16(z21, z31);
                *(uint4*)&zbf[g][(n31 + 32 * ct) * 8] = d;   // j = c*8+r*4+l
            }
        }
    }
    __syncthreads();   // zbf complete, visible to all waves

    // ------- Phase 2: MFMA 16x16x32, D[m=g][n=i], K=512, B = bf16 global ---
    const int m15 = lane & 15;          // A row g AND D col i
    const int q   = lane >> 4;          // k-quad
    f32x4 pa0, pa1;
    #pragma unroll
    for (int j = 0; j < 4; ++j) { pa0[j] = 0.f; pa1[j] = 0.f; }
    const int i0 = w * 32 + m15;
    const int i1 = w * 32 + 16 + m15;
    #pragma unroll 4
    for (int ks = 0; ks < 16; ++ks) {
        U8 Az, Bw0, Bw1;
        Az.q  = *(const uint4*)&zbf[m15][ks * 32 + q * 8];
        Bw0.q = *(const uint4*)&Wb[(size_t)i0 * 512 + ks * 32 + q * 8];
        Bw1.q = *(const uint4*)&Wb[(size_t)i1 * 512 + ks * 32 + q * 8];
        pa0 = __builtin_amdgcn_mfma_f32_16x16x32_bf16(Az.v, Bw0.v, pa0, 0, 0, 0);
        pa1 = __builtin_amdgcn_mfma_f32_16x16x32_bf16(Az.v, Bw1.v, pa1, 0, 0, 0);
    }
    const float bi0 = bias[i0], bi1 = bias[i1];
    #pragma unroll
    for (int reg = 0; reg < 4; ++reg) {
        const int g = q * 4 + reg;                       // D row = g
        const size_t row = ((size_t)b * kV + v_base + g) * 128;
        out[row + i0] = fmaxf(pa0[reg] + bi0, 0.f);
        out[row + i1] = fmaxf(pa1[reg] + bi1, 0.f);
    }
}

} // namespace

extern "C" void kernel_launch(void* const* d_in, const int* in_sizes, int n_in,
                              void* d_out, int out_size, void* d_ws, size_t ws_size,
                              hipStream_t stream) {
    const float* signal = (const float*)d_in[0];
    const int*   pidx   = (const int*)d_in[1];
    const float* ck     = (const float*)d_in[2];
    const float* W      = (const float*)d_in[3];
    const float* bias   = (const float*)d_in[4];
    float* out = (float*)d_out;
    unsigned* Wb = (unsigned*)d_ws;     // 128 KB bf16 weights

    convW<<<dim3(128), dim3(256), 0, stream>>>(W, Wb);
    fused<<<dim3(kBlocks), dim3(256), 0, stream>>>(
        signal, pidx, ck, (const unsigned short*)Wb, bias, out);
}